// Round 2
// baseline (469.833 us; speedup 1.0000x reference)
//
#include <hip/hip_runtime.h>
#include <math.h>

#define NTOK 65536
#define CDIM 256
#define DDIM 16
#define KCOD 4096
#define HWSZ 4096
#define CHUNK 512

// ---- ws layout (float offsets) ----
#define WS_BCS   0                        // [4096]  batch_cluster_size
#define WS_BES   (WS_BCS + KCOD)          // [65536] batch_embed_sum
#define WS_SCAL  (WS_BES + KCOD*DDIM)     // [8] 0=loss_sum 1=n_sum 2=ent_sum
#define WS_ENORM (WS_SCAL + 8)            // [65536] normalized codebook
#define WS_ENN   (WS_ENORM + KCOD*DDIM)   // [4096]  sum(e_norm^2)
#define WS_ZQL   (WS_ENN + KCOD)          // [1048576] z_q_low (straight-through)

// ---- out layout (float offsets) ----
#define OFS_ZQ   0
#define OFS_LOSS 16777216
#define OFS_IDX  16777217
#define OFS_ENT  16842753
#define OFS_NE   16842754
#define OFS_NCS  16908290
#define OFS_NEA  16912386

// ============ normalize codebook, compute sum(e^2) ============
__global__ __launch_bounds__(256) void knorm_kernel(const float* __restrict__ emb,
                                                    float* __restrict__ ws) {
  int k = blockIdx.x * 256 + threadIdx.x;
  const float4* src = (const float4*)emb + (size_t)k * 4;
  float4 t0 = src[0], t1 = src[1], t2 = src[2], t3 = src[3];
  float e[16] = {t0.x,t0.y,t0.z,t0.w, t1.x,t1.y,t1.z,t1.w,
                 t2.x,t2.y,t2.z,t2.w, t3.x,t3.y,t3.z,t3.w};
  float ss = 0.f;
  #pragma unroll
  for (int d = 0; d < 16; ++d) ss += e[d] * e[d];
  float dn = fmaxf(sqrtf(ss), 1e-12f);
  #pragma unroll
  for (int d = 0; d < 16; ++d) e[d] = e[d] / dn;
  float s2 = 0.f;
  #pragma unroll
  for (int d = 0; d < 16; ++d) s2 += e[d] * e[d];
  float4* dst = (float4*)(ws + WS_ENORM) + (size_t)k * 4;
  dst[0] = make_float4(e[0],e[1],e[2],e[3]);
  dst[1] = make_float4(e[4],e[5],e[6],e[7]);
  dst[2] = make_float4(e[8],e[9],e[10],e[11]);
  dst[3] = make_float4(e[12],e[13],e[14],e[15]);
  ws[WS_ENN + k] = s2;
}

// ============ fused: down-proj + normalize + argmin + scatter + loss + zql ============
__global__ __launch_bounds__(256) void kmain_kernel(const float* __restrict__ z,
                                                    const float* __restrict__ w_down,
                                                    const float* __restrict__ b_down,
                                                    float* __restrict__ ws,
                                                    float* __restrict__ out) {
  __shared__ float wdT[CDIM * DDIM];    // 16 KB, [c][d]
  __shared__ float ecache[CHUNK * DDIM]; // 32 KB
  __shared__ float encache[CHUNK];       // 2 KB

  const int tid = threadIdx.x;
  const int n = blockIdx.x * 256 + tid;
  const int b = n >> 12;
  const int hw = n & 4095;

  // stage w_down transposed: wdT[c*16+d] = w_down[d*256+c]; coalesced reads
  for (int i = tid; i < CDIM * DDIM; i += 256) {
    int d = i >> 8, c = i & 255;
    wdT[c * 16 + d] = w_down[i];
  }
  __syncthreads();

  // ---- phase 1: down-projection (seed 0, bias added after — matches ref order) ----
  const float* zp = z + (size_t)b * (CDIM * HWSZ) + hw;
  float acc[16];
  #pragma unroll
  for (int d = 0; d < 16; ++d) acc[d] = 0.f;
  #pragma unroll 16
  for (int c = 0; c < CDIM; ++c) {
    float zv = zp[(size_t)c * HWSZ];
    const float4* wr = (const float4*)(wdT + c * 16);
    float4 w0 = wr[0], w1 = wr[1], w2 = wr[2], w3 = wr[3];
    acc[0]  = fmaf(zv, w0.x, acc[0]);  acc[1]  = fmaf(zv, w0.y, acc[1]);
    acc[2]  = fmaf(zv, w0.z, acc[2]);  acc[3]  = fmaf(zv, w0.w, acc[3]);
    acc[4]  = fmaf(zv, w1.x, acc[4]);  acc[5]  = fmaf(zv, w1.y, acc[5]);
    acc[6]  = fmaf(zv, w1.z, acc[6]);  acc[7]  = fmaf(zv, w1.w, acc[7]);
    acc[8]  = fmaf(zv, w2.x, acc[8]);  acc[9]  = fmaf(zv, w2.y, acc[9]);
    acc[10] = fmaf(zv, w2.z, acc[10]); acc[11] = fmaf(zv, w2.w, acc[11]);
    acc[12] = fmaf(zv, w3.x, acc[12]); acc[13] = fmaf(zv, w3.y, acc[13]);
    acc[14] = fmaf(zv, w3.z, acc[14]); acc[15] = fmaf(zv, w3.w, acc[15]);
  }
  float zn[16];
  {
    #pragma unroll
    for (int d = 0; d < 16; ++d) acc[d] = acc[d] + b_down[d];
    float ss = 0.f;
    #pragma unroll
    for (int d = 0; d < 16; ++d) ss += acc[d] * acc[d];
    float dn = fmaxf(sqrtf(ss), 1e-12f);
    #pragma unroll
    for (int d = 0; d < 16; ++d) zn[d] = acc[d] / dn;
  }
  float znn = 0.f;
  {
    float sq[16];
    #pragma unroll
    for (int d = 0; d < 16; ++d) sq[d] = zn[d] * zn[d];
    #pragma unroll
    for (int d = 0; d < 16; ++d) znn += sq[d];
  }

  // ---- phase 2: argmin over K codes, LDS-chunked ----
  const float* en  = ws + WS_ENORM;
  const float* enp = ws + WS_ENN;
  float best = 3.4e38f;
  int bidx = 0;
  for (int kbase = 0; kbase < KCOD; kbase += CHUNK) {
    __syncthreads();
    {
      const float4* s4 = (const float4*)(en + (size_t)kbase * 16);
      float4* d4 = (float4*)ecache;
      for (int i = tid; i < CHUNK * 4; i += 256) d4[i] = s4[i];
      for (int i = tid; i < CHUNK; i += 256) encache[i] = enp[kbase + i];
    }
    __syncthreads();
    for (int j = 0; j < CHUNK; j += 2) {
      const float4* e0 = (const float4*)(ecache + j * 16);
      float4 a0 = e0[0], a1 = e0[1], a2 = e0[2], a3 = e0[3];
      float4 c0 = e0[4], c1 = e0[5], c2 = e0[6], c3 = e0[7];
      float d0 = 0.f, d1 = 0.f;
      d0 = fmaf(zn[0],  a0.x, d0); d1 = fmaf(zn[0],  c0.x, d1);
      d0 = fmaf(zn[1],  a0.y, d0); d1 = fmaf(zn[1],  c0.y, d1);
      d0 = fmaf(zn[2],  a0.z, d0); d1 = fmaf(zn[2],  c0.z, d1);
      d0 = fmaf(zn[3],  a0.w, d0); d1 = fmaf(zn[3],  c0.w, d1);
      d0 = fmaf(zn[4],  a1.x, d0); d1 = fmaf(zn[4],  c1.x, d1);
      d0 = fmaf(zn[5],  a1.y, d0); d1 = fmaf(zn[5],  c1.y, d1);
      d0 = fmaf(zn[6],  a1.z, d0); d1 = fmaf(zn[6],  c1.z, d1);
      d0 = fmaf(zn[7],  a1.w, d0); d1 = fmaf(zn[7],  c1.w, d1);
      d0 = fmaf(zn[8],  a2.x, d0); d1 = fmaf(zn[8],  c2.x, d1);
      d0 = fmaf(zn[9],  a2.y, d0); d1 = fmaf(zn[9],  c2.y, d1);
      d0 = fmaf(zn[10], a2.z, d0); d1 = fmaf(zn[10], c2.z, d1);
      d0 = fmaf(zn[11], a2.w, d0); d1 = fmaf(zn[11], c2.w, d1);
      d0 = fmaf(zn[12], a3.x, d0); d1 = fmaf(zn[12], c3.x, d1);
      d0 = fmaf(zn[13], a3.y, d0); d1 = fmaf(zn[13], c3.y, d1);
      d0 = fmaf(zn[14], a3.z, d0); d1 = fmaf(zn[14], c3.z, d1);
      d0 = fmaf(zn[15], a3.w, d0); d1 = fmaf(zn[15], c3.w, d1);
      float sc0 = fmaf(-2.0f, d0, znn) + encache[j];
      float sc1 = fmaf(-2.0f, d1, znn) + encache[j + 1];
      if (sc0 < best) { best = sc0; bidx = kbase + j; }
      if (sc1 < best) { best = sc1; bidx = kbase + j + 1; }
    }
  }

  // ---- epilogue ----
  float zq[16];
  {
    const float4* eb = (const float4*)(en + (size_t)bidx * 16);
    float4 q0 = eb[0], q1 = eb[1], q2 = eb[2], q3 = eb[3];
    zq[0]=q0.x; zq[1]=q0.y; zq[2]=q0.z; zq[3]=q0.w;
    zq[4]=q1.x; zq[5]=q1.y; zq[6]=q1.z; zq[7]=q1.w;
    zq[8]=q2.x; zq[9]=q2.y; zq[10]=q2.z; zq[11]=q2.w;
    zq[12]=q3.x; zq[13]=q3.y; zq[14]=q3.z; zq[15]=q3.w;
  }
  float ls = 0.f;
  #pragma unroll
  for (int d = 0; d < 16; ++d) { float df = zn[d] - zq[d]; ls = fmaf(df, df, ls); }

  // straight-through z_q_low = z_norm + (z_q - z_norm), written as ref computes it
  float ql[16];
  #pragma unroll
  for (int d = 0; d < 16; ++d) ql[d] = zn[d] + (zq[d] - zn[d]);
  {
    float4* qp = (float4*)(ws + WS_ZQL) + (size_t)n * 4;
    qp[0] = make_float4(ql[0],ql[1],ql[2],ql[3]);
    qp[1] = make_float4(ql[4],ql[5],ql[6],ql[7]);
    qp[2] = make_float4(ql[8],ql[9],ql[10],ql[11]);
    qp[3] = make_float4(ql[12],ql[13],ql[14],ql[15]);
  }
  out[OFS_IDX + n] = (float)bidx;

  atomicAdd(ws + WS_BCS + bidx, 1.0f);
  #pragma unroll
  for (int d = 0; d < 16; ++d) atomicAdd(ws + WS_BES + (size_t)bidx * 16 + d, zn[d]);

  // loss: wave reduce then one atomic per wave
  #pragma unroll
  for (int off = 32; off > 0; off >>= 1) ls += __shfl_down(ls, off, 64);
  if ((tid & 63) == 0) atomicAdd(ws + WS_SCAL + 0, ls);
}

// ============ up-projection ============
__global__ __launch_bounds__(256) void kup_kernel(const float* __restrict__ zql,
                                                  const float* __restrict__ w_up,
                                                  const float* __restrict__ b_up,
                                                  float* __restrict__ out) {
  __shared__ float wu[CDIM * DDIM]; // w_up already [C][D] row-major
  __shared__ float bu[CDIM];
  const int tid = threadIdx.x;
  {
    const float4* s4 = (const float4*)w_up;
    float4* d4 = (float4*)wu;
    for (int i = tid; i < CDIM * DDIM / 4; i += 256) d4[i] = s4[i];
    bu[tid] = b_up[tid];
  }
  __syncthreads();

  const int tok = blockIdx.x * 256 + tid;
  const float4* zp = (const float4*)zql + (size_t)tok * 4;
  float4 z0 = zp[0], z1 = zp[1], z2 = zp[2], z3 = zp[3];
  const int b = tok >> 12, hw = tok & 4095;
  float* op = out + OFS_ZQ + (size_t)b * (CDIM * HWSZ) + hw;

  #pragma unroll 4
  for (int c = 0; c < CDIM; ++c) {
    const float4* wr = (const float4*)(wu + c * 16);
    float4 w0 = wr[0], w1 = wr[1], w2 = wr[2], w3 = wr[3];
    float a = 0.f;
    a = fmaf(z0.x, w0.x, a); a = fmaf(z0.y, w0.y, a);
    a = fmaf(z0.z, w0.z, a); a = fmaf(z0.w, w0.w, a);
    a = fmaf(z1.x, w1.x, a); a = fmaf(z1.y, w1.y, a);
    a = fmaf(z1.z, w1.z, a); a = fmaf(z1.w, w1.w, a);
    a = fmaf(z2.x, w2.x, a); a = fmaf(z2.y, w2.y, a);
    a = fmaf(z2.z, w2.z, a); a = fmaf(z2.w, w2.w, a);
    a = fmaf(z3.x, w3.x, a); a = fmaf(z3.y, w3.y, a);
    a = fmaf(z3.z, w3.z, a); a = fmaf(z3.w, w3.w, a);
    a = a + bu[c];
    op[(size_t)c * HWSZ] = a;
  }
}

// ============ EMA buffers + partial sums (n, entropy) ============
__global__ __launch_bounds__(256) void kema_kernel(const float* __restrict__ cluster_size,
                                                   const float* __restrict__ embed_avg,
                                                   float* __restrict__ ws,
                                                   float* __restrict__ out) {
  const float DEC = 0.99f;
  const float OMD = (float)(1.0 - 0.99); // matches (1.0 - DECAY) cast to f32
  const int k = blockIdx.x * 256 + threadIdx.x;
  float bcsv = ws[WS_BCS + k];
  float ncs = cluster_size[k] * DEC + OMD * bcsv;
  out[OFS_NCS + k] = ncs;
  #pragma unroll
  for (int d = 0; d < 16; ++d) {
    float nea = embed_avg[(size_t)k * 16 + d] * DEC + OMD * ws[WS_BES + (size_t)k * 16 + d];
    out[OFS_NEA + (size_t)k * 16 + d] = nea;
  }
  // entropy term: sum(bcs) == 65536 exactly (integer-valued fp32 partial sums)
  float p = bcsv / 65536.0f;
  float et = -p * logf(p + 1e-8f);

  __shared__ float r1[4], r2[4];
  float v1 = ncs, v2 = et;
  #pragma unroll
  for (int off = 32; off > 0; off >>= 1) {
    v1 += __shfl_down(v1, off, 64);
    v2 += __shfl_down(v2, off, 64);
  }
  int lane = threadIdx.x & 63, w = threadIdx.x >> 6;
  if (lane == 0) { r1[w] = v1; r2[w] = v2; }
  __syncthreads();
  if (threadIdx.x == 0) {
    atomicAdd(ws + WS_SCAL + 1, (r1[0] + r1[1]) + (r1[2] + r1[3]));
    atomicAdd(ws + WS_SCAL + 2, (r2[0] + r2[1]) + (r2[2] + r2[3]));
  }
}

// ============ scalar outputs ============
__global__ __launch_bounds__(64) void kscal_kernel(const float* __restrict__ ws,
                                                   float* __restrict__ out) {
  if (threadIdx.x == 0) {
    out[OFS_LOSS] = 0.25f * (ws[WS_SCAL + 0] / 1048576.0f); // BETA * mean
    out[OFS_ENT]  = (float)8.317766166719343 - ws[WS_SCAL + 2]; // ln(4096) - entropy
  }
}

// ============ new_embedding = new_embed_avg / cs ============
__global__ __launch_bounds__(256) void kemb_kernel(const float* __restrict__ ws,
                                                   float* __restrict__ out) {
  const float KEPS = (float)(4096.0 * 1e-5);
  const int k = blockIdx.x * 256 + threadIdx.x;
  float n = ws[WS_SCAL + 1];
  float ncs = out[OFS_NCS + k];
  float cs = (ncs + 1e-5f) / (n + KEPS) * n;
  #pragma unroll
  for (int d = 0; d < 16; ++d)
    out[OFS_NE + (size_t)k * 16 + d] = out[OFS_NEA + (size_t)k * 16 + d] / cs;
}

extern "C" void kernel_launch(void* const* d_in, const int* in_sizes, int n_in,
                              void* d_out, int out_size, void* d_ws, size_t ws_size,
                              hipStream_t stream) {
  const float* z        = (const float*)d_in[0];
  const float* w_down   = (const float*)d_in[1];
  const float* b_down   = (const float*)d_in[2];
  const float* w_up     = (const float*)d_in[3];
  const float* b_up     = (const float*)d_in[4];
  const float* emb      = (const float*)d_in[5];
  const float* csz      = (const float*)d_in[6];
  const float* eavg     = (const float*)d_in[7];
  float* out = (float*)d_out;
  float* ws  = (float*)d_ws;

  // zero the accumulators (bcs + bes + scalars) — inside the graph, every replay
  hipMemsetAsync(ws, 0, (size_t)(WS_SCAL + 8) * sizeof(float), stream);

  knorm_kernel<<<KCOD / 256, 256, 0, stream>>>(emb, ws);
  kmain_kernel<<<NTOK / 256, 256, 0, stream>>>(z, w_down, b_down, ws, out);
  kup_kernel<<<NTOK / 256, 256, 0, stream>>>(ws + WS_ZQL, w_up, b_up, out);
  kema_kernel<<<KCOD / 256, 256, 0, stream>>>(csz, eavg, ws, out);
  kscal_kernel<<<1, 64, 0, stream>>>(ws, out);
  kemb_kernel<<<KCOD / 256, 256, 0, stream>>>(ws, out);
}

// Round 3
// 247.938 us; speedup vs baseline: 1.8950x; 1.8950x over previous
//
#include <hip/hip_runtime.h>
#include <math.h>

#define NTOK 65536
#define CDIM 256
#define DDIM 16
#define KCOD 4096
#define HWSZ 4096

#define KSPLIT 16
#define CPS (KCOD / KSPLIT)   // 256 codes per split-block
#define TPT 8                 // tokens per thread in kscan
#define TBLK (256 * TPT)      // 2048 tokens per kscan block

// ---- ws layout (float offsets) ----
#define WS_ENORM 0                         // [65536] normalized codebook
#define WS_ENN   (WS_ENORM + KCOD*DDIM)    // [4096]  sum(e_norm^2)
#define WS_ZN    (WS_ENN + KCOD)           // [1048576] z_norm [N,16]
#define WS_ZNN   (WS_ZN + NTOK*DDIM)       // [65536] sum(z_norm^2)
#define WS_BCS   (WS_ZNN + NTOK)           // [4096]  batch_cluster_size
#define WS_BES   (WS_BCS + KCOD)           // [65536] batch_embed_sum
#define WS_SCAL  (WS_BES + KCOD*DDIM)      // [8] 0=loss_sum 1=n_sum 2=ent_sum
#define WS_PACK  (WS_SCAL + 8)             // [65536 x u64] packed (score,idx)
// WS_PACK float-offset 1253384 -> byte 5013536, 8B aligned.

// ---- out layout (float offsets) ----
#define OFS_ZQ   0
#define OFS_LOSS 16777216
#define OFS_IDX  16777217
#define OFS_ENT  16842753
#define OFS_NE   16842754
#define OFS_NCS  16908290
#define OFS_NEA  16912386

// ============ normalize codebook, compute sum(e^2) ============
__global__ __launch_bounds__(256) void knorm_kernel(const float* __restrict__ emb,
                                                    float* __restrict__ ws) {
  int k = blockIdx.x * 256 + threadIdx.x;
  const float4* src = (const float4*)emb + (size_t)k * 4;
  float4 t0 = src[0], t1 = src[1], t2 = src[2], t3 = src[3];
  float e[16] = {t0.x,t0.y,t0.z,t0.w, t1.x,t1.y,t1.z,t1.w,
                 t2.x,t2.y,t2.z,t2.w, t3.x,t3.y,t3.z,t3.w};
  float ss = 0.f;
  #pragma unroll
  for (int d = 0; d < 16; ++d) ss += e[d] * e[d];
  float dn = fmaxf(sqrtf(ss), 1e-12f);
  #pragma unroll
  for (int d = 0; d < 16; ++d) e[d] = e[d] / dn;
  float s2 = 0.f;
  #pragma unroll
  for (int d = 0; d < 16; ++d) s2 += e[d] * e[d];
  float4* dst = (float4*)(ws + WS_ENORM) + (size_t)k * 4;
  dst[0] = make_float4(e[0],e[1],e[2],e[3]);
  dst[1] = make_float4(e[4],e[5],e[6],e[7]);
  dst[2] = make_float4(e[8],e[9],e[10],e[11]);
  dst[3] = make_float4(e[12],e[13],e[14],e[15]);
  ws[WS_ENN + k] = s2;
}

// ============ down-proj + L2-normalize -> ws ZN/ZNN ============
__global__ __launch_bounds__(256) void kdown_kernel(const float* __restrict__ z,
                                                    const float* __restrict__ w_down,
                                                    const float* __restrict__ b_down,
                                                    float* __restrict__ ws) {
  __shared__ float wdT[CDIM * DDIM]; // [c][d]
  const int tid = threadIdx.x;
  const int n = blockIdx.x * 256 + tid;
  const int b = n >> 12;
  const int hw = n & 4095;

  for (int i = tid; i < CDIM * DDIM; i += 256) {
    int d = i >> 8, c = i & 255;
    wdT[c * 16 + d] = w_down[i];
  }
  __syncthreads();

  const float* zp = z + (size_t)b * (CDIM * HWSZ) + hw;
  float acc[16];
  #pragma unroll
  for (int d = 0; d < 16; ++d) acc[d] = 0.f;
  #pragma unroll 16
  for (int c = 0; c < CDIM; ++c) {
    float zv = zp[(size_t)c * HWSZ];
    const float4* wr = (const float4*)(wdT + c * 16);
    float4 w0 = wr[0], w1 = wr[1], w2 = wr[2], w3 = wr[3];
    acc[0]  = fmaf(zv, w0.x, acc[0]);  acc[1]  = fmaf(zv, w0.y, acc[1]);
    acc[2]  = fmaf(zv, w0.z, acc[2]);  acc[3]  = fmaf(zv, w0.w, acc[3]);
    acc[4]  = fmaf(zv, w1.x, acc[4]);  acc[5]  = fmaf(zv, w1.y, acc[5]);
    acc[6]  = fmaf(zv, w1.z, acc[6]);  acc[7]  = fmaf(zv, w1.w, acc[7]);
    acc[8]  = fmaf(zv, w2.x, acc[8]);  acc[9]  = fmaf(zv, w2.y, acc[9]);
    acc[10] = fmaf(zv, w2.z, acc[10]); acc[11] = fmaf(zv, w2.w, acc[11]);
    acc[12] = fmaf(zv, w3.x, acc[12]); acc[13] = fmaf(zv, w3.y, acc[13]);
    acc[14] = fmaf(zv, w3.z, acc[14]); acc[15] = fmaf(zv, w3.w, acc[15]);
  }
  #pragma unroll
  for (int d = 0; d < 16; ++d) acc[d] = acc[d] + b_down[d];
  float ss = 0.f;
  #pragma unroll
  for (int d = 0; d < 16; ++d) ss += acc[d] * acc[d];
  float dn = fmaxf(sqrtf(ss), 1e-12f);
  float zn[16];
  #pragma unroll
  for (int d = 0; d < 16; ++d) zn[d] = acc[d] / dn;
  float znn = 0.f;
  {
    float sq[16];
    #pragma unroll
    for (int d = 0; d < 16; ++d) sq[d] = zn[d] * zn[d];
    #pragma unroll
    for (int d = 0; d < 16; ++d) znn += sq[d];
  }
  float4* op = (float4*)(ws + WS_ZN) + (size_t)n * 4;
  op[0] = make_float4(zn[0],zn[1],zn[2],zn[3]);
  op[1] = make_float4(zn[4],zn[5],zn[6],zn[7]);
  op[2] = make_float4(zn[8],zn[9],zn[10],zn[11]);
  op[3] = make_float4(zn[12],zn[13],zn[14],zn[15]);
  ws[WS_ZNN + n] = znn;
}

// ============ argmin scan: K split 16 ways, 8 tokens/thread ============
__global__ __launch_bounds__(256) void kscan_kernel(float* __restrict__ ws) {
  __shared__ float ecache[CPS * DDIM]; // 16 KB
  __shared__ float encache[CPS];       // 1 KB

  const int tid = threadIdx.x;
  const int kbase = blockIdx.y * CPS;

  {
    const float4* s4 = (const float4*)(ws + WS_ENORM + (size_t)kbase * 16);
    float4* d4 = (float4*)ecache;
    #pragma unroll
    for (int i = 0; i < 4; ++i) d4[tid + i * 256] = s4[tid + i * 256];
    encache[tid] = ws[WS_ENN + kbase + tid];
  }
  __syncthreads();

  // load 8 tokens' z_norm into registers
  float zn[TPT][16];
  float znn[TPT], best[TPT];
  int bidx[TPT];
  const int tokbase = blockIdx.x * TBLK + tid;
  {
    const float4* zp = (const float4*)(ws + WS_ZN);
    #pragma unroll
    for (int p = 0; p < TPT; ++p) {
      int tok = tokbase + p * 256;
      float4 a0 = zp[(size_t)tok * 4 + 0];
      float4 a1 = zp[(size_t)tok * 4 + 1];
      float4 a2 = zp[(size_t)tok * 4 + 2];
      float4 a3 = zp[(size_t)tok * 4 + 3];
      zn[p][0]=a0.x; zn[p][1]=a0.y; zn[p][2]=a0.z; zn[p][3]=a0.w;
      zn[p][4]=a1.x; zn[p][5]=a1.y; zn[p][6]=a1.z; zn[p][7]=a1.w;
      zn[p][8]=a2.x; zn[p][9]=a2.y; zn[p][10]=a2.z; zn[p][11]=a2.w;
      zn[p][12]=a3.x; zn[p][13]=a3.y; zn[p][14]=a3.z; zn[p][15]=a3.w;
      znn[p] = ws[WS_ZNN + tok];
      best[p] = 3.4e38f;
      bidx[p] = 0;
    }
  }

  #pragma unroll 2
  for (int j = 0; j < CPS; ++j) {
    const float4* e4 = (const float4*)(ecache + j * 16);
    float4 c0 = e4[0], c1 = e4[1], c2 = e4[2], c3 = e4[3];
    float en = encache[j];
    #pragma unroll
    for (int p = 0; p < TPT; ++p) {
      float d = 0.f;
      d = fmaf(zn[p][0],  c0.x, d); d = fmaf(zn[p][1],  c0.y, d);
      d = fmaf(zn[p][2],  c0.z, d); d = fmaf(zn[p][3],  c0.w, d);
      d = fmaf(zn[p][4],  c1.x, d); d = fmaf(zn[p][5],  c1.y, d);
      d = fmaf(zn[p][6],  c1.z, d); d = fmaf(zn[p][7],  c1.w, d);
      d = fmaf(zn[p][8],  c2.x, d); d = fmaf(zn[p][9],  c2.y, d);
      d = fmaf(zn[p][10], c2.z, d); d = fmaf(zn[p][11], c2.w, d);
      d = fmaf(zn[p][12], c3.x, d); d = fmaf(zn[p][13], c3.y, d);
      d = fmaf(zn[p][14], c3.z, d); d = fmaf(zn[p][15], c3.w, d);
      float sc = fmaf(-2.0f, d, znn[p]) + en;
      if (sc < best[p]) { best[p] = sc; bidx[p] = j; }
    }
  }

  // merge across splits: packed (ordered-score, idx) atomicMin -> exact
  // lowest-index tie-break like jnp.argmin
  unsigned long long* packp = (unsigned long long*)(ws + WS_PACK);
  #pragma unroll
  for (int p = 0; p < TPT; ++p) {
    int tok = tokbase + p * 256;
    unsigned u = __float_as_uint(best[p]);
    u = (u & 0x80000000u) ? ~u : (u | 0x80000000u);
    unsigned long long key =
        ((unsigned long long)u << 32) | (unsigned)(kbase + bidx[p]);
    atomicMin(packp + tok, key);
  }
}

// ============ merge + scatter + loss + fused up-projection ============
__global__ __launch_bounds__(256) void kfinal_kernel(const float* __restrict__ w_up,
                                                     const float* __restrict__ b_up,
                                                     float* __restrict__ ws,
                                                     float* __restrict__ out) {
  __shared__ float wu[CDIM * DDIM]; // w_up [C][D] row-major
  __shared__ float bu[CDIM];
  const int tid = threadIdx.x;
  {
    const float4* s4 = (const float4*)w_up;
    float4* d4 = (float4*)wu;
    #pragma unroll
    for (int i = 0; i < 4; ++i) d4[tid + i * 256] = s4[tid + i * 256];
    bu[tid] = b_up[tid];
  }
  __syncthreads();

  const int n = blockIdx.x * 256 + tid;
  const unsigned long long* packp = (const unsigned long long*)(ws + WS_PACK);
  const int bidx = (int)(unsigned)(packp[n] & 0xFFFFFFFFull);

  float zn[16];
  {
    const float4* zp = (const float4*)(ws + WS_ZN) + (size_t)n * 4;
    float4 a0 = zp[0], a1 = zp[1], a2 = zp[2], a3 = zp[3];
    zn[0]=a0.x; zn[1]=a0.y; zn[2]=a0.z; zn[3]=a0.w;
    zn[4]=a1.x; zn[5]=a1.y; zn[6]=a1.z; zn[7]=a1.w;
    zn[8]=a2.x; zn[9]=a2.y; zn[10]=a2.z; zn[11]=a2.w;
    zn[12]=a3.x; zn[13]=a3.y; zn[14]=a3.z; zn[15]=a3.w;
  }
  float zq[16];
  {
    const float4* eb = (const float4*)(ws + WS_ENORM) + (size_t)bidx * 4;
    float4 q0 = eb[0], q1 = eb[1], q2 = eb[2], q3 = eb[3];
    zq[0]=q0.x; zq[1]=q0.y; zq[2]=q0.z; zq[3]=q0.w;
    zq[4]=q1.x; zq[5]=q1.y; zq[6]=q1.z; zq[7]=q1.w;
    zq[8]=q2.x; zq[9]=q2.y; zq[10]=q2.z; zq[11]=q2.w;
    zq[12]=q3.x; zq[13]=q3.y; zq[14]=q3.z; zq[15]=q3.w;
  }

  out[OFS_IDX + n] = (float)bidx;

  float ls = 0.f;
  #pragma unroll
  for (int d = 0; d < 16; ++d) { float df = zn[d] - zq[d]; ls = fmaf(df, df, ls); }

  atomicAdd(ws + WS_BCS + bidx, 1.0f);
  #pragma unroll
  for (int d = 0; d < 16; ++d) atomicAdd(ws + WS_BES + (size_t)bidx * 16 + d, zn[d]);

  #pragma unroll
  for (int off = 32; off > 0; off >>= 1) ls += __shfl_down(ls, off, 64);
  if ((tid & 63) == 0) atomicAdd(ws + WS_SCAL + 0, ls);

  // straight-through value: ql = zn + (zq - zn), same fp ops as the ref
  float ql[16];
  #pragma unroll
  for (int d = 0; d < 16; ++d) ql[d] = zn[d] + (zq[d] - zn[d]);

  const int b = n >> 12, hw = n & 4095;
  float* op = out + OFS_ZQ + (size_t)b * (CDIM * HWSZ) + hw;
  #pragma unroll 4
  for (int c = 0; c < CDIM; ++c) {
    const float4* wr = (const float4*)(wu + c * 16);
    float4 w0 = wr[0], w1 = wr[1], w2 = wr[2], w3 = wr[3];
    float a = 0.f;
    a = fmaf(ql[0],  w0.x, a); a = fmaf(ql[1],  w0.y, a);
    a = fmaf(ql[2],  w0.z, a); a = fmaf(ql[3],  w0.w, a);
    a = fmaf(ql[4],  w1.x, a); a = fmaf(ql[5],  w1.y, a);
    a = fmaf(ql[6],  w1.z, a); a = fmaf(ql[7],  w1.w, a);
    a = fmaf(ql[8],  w2.x, a); a = fmaf(ql[9],  w2.y, a);
    a = fmaf(ql[10], w2.z, a); a = fmaf(ql[11], w2.w, a);
    a = fmaf(ql[12], w3.x, a); a = fmaf(ql[13], w3.y, a);
    a = fmaf(ql[14], w3.z, a); a = fmaf(ql[15], w3.w, a);
    a = a + bu[c];
    op[(size_t)c * HWSZ] = a;
  }
}

// ============ EMA buffers + partial sums (n, entropy) ============
__global__ __launch_bounds__(256) void kema_kernel(const float* __restrict__ cluster_size,
                                                   const float* __restrict__ embed_avg,
                                                   float* __restrict__ ws,
                                                   float* __restrict__ out) {
  const float DEC = 0.99f;
  const float OMD = (float)(1.0 - 0.99);
  const int k = blockIdx.x * 256 + threadIdx.x;
  float bcsv = ws[WS_BCS + k];
  float ncs = cluster_size[k] * DEC + OMD * bcsv;
  out[OFS_NCS + k] = ncs;
  #pragma unroll
  for (int d = 0; d < 16; ++d) {
    float nea = embed_avg[(size_t)k * 16 + d] * DEC + OMD * ws[WS_BES + (size_t)k * 16 + d];
    out[OFS_NEA + (size_t)k * 16 + d] = nea;
  }
  // sum(bcs) == 65536 exactly (integer-valued fp32)
  float p = bcsv / 65536.0f;
  float et = -p * logf(p + 1e-8f);

  __shared__ float r1[4], r2[4];
  float v1 = ncs, v2 = et;
  #pragma unroll
  for (int off = 32; off > 0; off >>= 1) {
    v1 += __shfl_down(v1, off, 64);
    v2 += __shfl_down(v2, off, 64);
  }
  int lane = threadIdx.x & 63, w = threadIdx.x >> 6;
  if (lane == 0) { r1[w] = v1; r2[w] = v2; }
  __syncthreads();
  if (threadIdx.x == 0) {
    atomicAdd(ws + WS_SCAL + 1, (r1[0] + r1[1]) + (r1[2] + r1[3]));
    atomicAdd(ws + WS_SCAL + 2, (r2[0] + r2[1]) + (r2[2] + r2[3]));
  }
}

// ============ scalar outputs ============
__global__ __launch_bounds__(64) void kscal_kernel(const float* __restrict__ ws,
                                                   float* __restrict__ out) {
  if (threadIdx.x == 0) {
    out[OFS_LOSS] = 0.25f * (ws[WS_SCAL + 0] / 1048576.0f);
    out[OFS_ENT]  = (float)8.317766166719343 - ws[WS_SCAL + 2];
  }
}

// ============ new_embedding = new_embed_avg / cs ============
__global__ __launch_bounds__(256) void kemb_kernel(const float* __restrict__ ws,
                                                   float* __restrict__ out) {
  const float KEPS = (float)(4096.0 * 1e-5);
  const int k = blockIdx.x * 256 + threadIdx.x;
  float n = ws[WS_SCAL + 1];
  float ncs = out[OFS_NCS + k];
  float cs = (ncs + 1e-5f) / (n + KEPS) * n;
  #pragma unroll
  for (int d = 0; d < 16; ++d)
    out[OFS_NE + (size_t)k * 16 + d] = out[OFS_NEA + (size_t)k * 16 + d] / cs;
}

extern "C" void kernel_launch(void* const* d_in, const int* in_sizes, int n_in,
                              void* d_out, int out_size, void* d_ws, size_t ws_size,
                              hipStream_t stream) {
  const float* z        = (const float*)d_in[0];
  const float* w_down   = (const float*)d_in[1];
  const float* b_down   = (const float*)d_in[2];
  const float* w_up     = (const float*)d_in[3];
  const float* b_up     = (const float*)d_in[4];
  const float* emb      = (const float*)d_in[5];
  const float* csz      = (const float*)d_in[6];
  const float* eavg     = (const float*)d_in[7];
  float* out = (float*)d_out;
  float* ws  = (float*)d_ws;

  // zero accumulators (bcs+bes+scal); init packed argmin keys to +inf
  hipMemsetAsync(ws + WS_BCS, 0, (size_t)(KCOD + KCOD*DDIM + 8) * sizeof(float), stream);
  hipMemsetAsync(ws + WS_PACK, 0xFF, (size_t)NTOK * 8, stream);

  knorm_kernel<<<KCOD / 256, 256, 0, stream>>>(emb, ws);
  kdown_kernel<<<NTOK / 256, 256, 0, stream>>>(z, w_down, b_down, ws);
  kscan_kernel<<<dim3(NTOK / TBLK, KSPLIT), 256, 0, stream>>>(ws);
  kfinal_kernel<<<NTOK / 256, 256, 0, stream>>>(w_up, b_up, ws, out);
  kema_kernel<<<KCOD / 256, 256, 0, stream>>>(csz, eavg, ws, out);
  kscal_kernel<<<1, 64, 0, stream>>>(ws, out);
  kemb_kernel<<<KCOD / 256, 256, 0, stream>>>(ws, out);
}